// Round 4
// baseline (135.153 us; speedup 1.0000x reference)
//
#include <hip/hip_runtime.h>
#include <hip/hip_bf16.h>
#include <stdint.h>

typedef uint32_t u32;
typedef uint64_t u64;

// Problem constants (from reference)
constexpr int BATCH = 8;
constexpr int L = 32768;
constexpr int C = 128;            // channels
constexpr int N = BATCH * L;      // 262144 points
constexpr int NBUCKET = 1 << 14;  // buckets on top-14 bits of 30-bit key
constexpr u32 DUP_CAP = 131072;   // dupList capacity (reuses dead 'keys' buffer)
// key = (batch<<27)|(x<<18)|(y<<9)|z  (30 bits); bucket = key >> 16
// Buckets partition keys => every bucket start is a segment head; head ranking
// is bucket-local + exclusive scan of per-bucket head counts.

// ---------------- K1: keys + bucket histogram ----------------
__global__ __launch_bounds__(256) void k_keys_hist(const int* __restrict__ coords,
                                                   int* __restrict__ keys,
                                                   u32* __restrict__ hist) {
    int i = blockIdx.x * 256 + threadIdx.x;
    int batch = i >> 15;  // i / L
    int x = coords[3 * i + 0];
    int y = coords[3 * i + 1];
    int z = coords[3 * i + 2];
    int key = (batch << 27) | (x << 18) | (y << 9) | z;
    keys[i] = key;
    atomicAdd(&hist[(u32)key >> 16], 1u);
}

// ---------------- K2: exclusive scan of 16384 u32 counts (1 block) ----------------
// Used twice: hist->bstart and hcnt->hoff. Writes out[NBUCKET] = total.
__global__ __launch_bounds__(1024) void k_scan_buckets(const u32* __restrict__ cnt,
                                                       u32* __restrict__ outp) {
    __shared__ u32 s[1024];
    int t = threadIdx.x;
    u32 loc[16];
    u32 sum = 0;
    for (int k = 0; k < 16; ++k) { loc[k] = sum; sum += cnt[t * 16 + k]; }
    s[t] = sum;
    __syncthreads();
    for (int off = 1; off < 1024; off <<= 1) {
        u32 v = (t >= off) ? s[t - off] : 0u;
        __syncthreads();
        s[t] += v;
        __syncthreads();
    }
    u32 base = (t == 0) ? 0u : s[t - 1];
    for (int k = 0; k < 16; ++k) outp[t * 16 + k] = base + loc[k];
    if (t == 1023) outp[NBUCKET] = s[1023];
}

// ---------------- K3: scatter packed (key,idx) into bucket-contiguous order ----------------
__global__ __launch_bounds__(256) void k_scatter(const int* __restrict__ keys,
                                                 const u32* __restrict__ bstart,
                                                 u32* __restrict__ cursor,
                                                 u64* __restrict__ bucketed) {
    int i = blockIdx.x * 256 + threadIdx.x;
    u32 key = (u32)keys[i];
    u32 b = key >> 16;
    u32 pos = bstart[b] + atomicAdd(&cursor[b], 1u);
    bucketed[pos] = ((u64)key << 32) | (u32)i;
}

// ---------------- K4: per-bucket exact sort + distinct-key count ----------------
// Grid-stride over buckets: 1024 blocks x 64 threads (1 wave), ~16 buckets each.
__global__ __launch_bounds__(64) void k_sort_buckets(const u32* __restrict__ bstart,
                                                     const u64* __restrict__ bucketed,
                                                     u64* __restrict__ sorted,
                                                     u32* __restrict__ hcnt) {
    __shared__ u64 lds[1024];
    int lane = threadIdx.x;
    for (int b = blockIdx.x; b < NBUCKET; b += gridDim.x) {
        u32 s0 = bstart[b];
        u32 e = bstart[b + 1];
        int m = (int)(e - s0);
        if (m <= 0) { if (lane == 0) hcnt[b] = 0; continue; }
        int hloc = 0;
        if (m <= 1024) {
            for (int k = lane; k < m; k += 64) lds[k] = bucketed[s0 + k];
            __syncthreads();
            for (int j = lane; j < m; j += 64) {
                u64 v = lds[j];
                u32 vk = (u32)(v >> 32);
                int cnt = 0, eqb = 0;
                for (int k = 0; k < m; ++k) {
                    u64 w = lds[k];
                    cnt += (w < v) ? 1 : 0;
                    eqb += ((k < j) && ((u32)(w >> 32) == vk)) ? 1 : 0;
                }
                sorted[s0 + cnt] = v;
                hloc += (eqb == 0) ? 1 : 0;  // first occurrence of this key
            }
            __syncthreads();  // protect lds reuse next bucket
        } else {  // safety fallback (won't trigger for uniform random input)
            for (int j = lane; j < m; j += 64) {
                u64 v = bucketed[s0 + j];
                u32 vk = (u32)(v >> 32);
                int cnt = 0, eqb = 0;
                for (int k = 0; k < m; ++k) {
                    u64 w = bucketed[s0 + k];
                    cnt += (w < v) ? 1 : 0;
                    eqb += ((k < j) && ((u32)(w >> 32) == vk)) ? 1 : 0;
                }
                sorted[s0 + cnt] = v;
                hloc += (eqb == 0) ? 1 : 0;
            }
        }
        for (int off = 32; off > 0; off >>= 1) hloc += __shfl_down(hloc, off);
        if (lane == 0) hcnt[b] = (u32)hloc;
    }
}

// ---------------- K5: build inverse map + duplicate list (one wave per bucket) ----------------
__global__ __launch_bounds__(256) void k_build_inv(const u32* __restrict__ bstart,
                                                   const u64* __restrict__ sorted,
                                                   const u32* __restrict__ hoff,
                                                   int* __restrict__ inv,
                                                   u64* __restrict__ dupList,
                                                   u32* __restrict__ dupCount) {
    int wid = (blockIdx.x * 256 + threadIdx.x) >> 6;
    int nw = (gridDim.x * 256) >> 6;
    int lane = threadIdx.x & 63;
    for (int b = wid; b < NBUCKET; b += nw) {
        u32 s0 = bstart[b];
        u32 m = bstart[b + 1] - s0;
        if (m == 0) continue;
        u32 hbase = hoff[b];
        u32 localHeads = 0;
        u32 prevKeyLast = 0;
        bool first = true;
        for (u32 base = 0; base < m; base += 64) {
            u32 j = base + (u32)lane;
            u64 v = (j < m) ? sorted[s0 + j] : 0ull;
            u32 key = (u32)(v >> 32);
            u32 keyPrev = (u32)__shfl_up((int)key, 1);
            if (lane == 0) keyPrev = first ? (key + 1u) : prevKeyLast;
            bool head = (j < m) && (key != keyPrev);
            u64 bal = __ballot(head);
            u32 localIdx = localHeads + (u32)__popcll(bal & ((1ull << lane) - 1ull));
            u32 keyNext = (u32)__shfl_down((int)key, 1);
            bool nextSame;
            if (j + 1 >= m) nextSame = false;
            else if (lane == 63) nextSame = ((u32)(sorted[s0 + j + 1] >> 32) == key);
            else nextSame = (keyNext == key);
            if (j < m) {
                u32 p = (u32)v;  // original point index
                if (head && !nextSame) {
                    inv[p] = (int)(hbase + localIdx);  // singleton: direct copy row
                } else {
                    inv[p] = -1;  // duplicate-segment member (incl. head)
                    if (head) {
                        u32 slot = atomicAdd(dupCount, 1u);
                        if (slot < DUP_CAP)
                            dupList[slot] = ((u64)(hbase + localIdx) << 32) | (s0 + j);
                    }
                }
            }
            localHeads += (u32)__popcll(bal);
            u32 lastValid = (m - base - 1 < 63u) ? (m - base - 1) : 63u;
            prevKeyLast = (u32)__shfl((int)key, (int)lastValid);
            first = false;
        }
    }
}

// ---------------- K6: streaming scatter of features (read seq, write scattered) ----------------
constexpr int ROWS_PER_BLOCK = 8;
__global__ __launch_bounds__(256) void k_scatter_feats(const int* __restrict__ inv,
                                                       const float* __restrict__ feats,
                                                       float* __restrict__ out) {
    int p = blockIdx.x * ROWS_PER_BLOCK + (threadIdx.x >> 5);
    int q = threadIdx.x & 31;  // float4 slot within the 128-ch row
    int r = inv[p];
    float4 v = ((const float4*)feats)[(size_t)p * 32 + q];
    if (r >= 0) {
        ((float4*)out)[(size_t)r * 32 + q] = v;
    }
}

// ---------------- K7: fixups — duplicate segments (exact order) + zero tail rows ----------------
__global__ __launch_bounds__(256) void k_fixup(const u64* __restrict__ sorted,
                                               const u64* __restrict__ dupList,
                                               const u32* __restrict__ dupCount,
                                               const u32* __restrict__ hoff,
                                               const float* __restrict__ feats,
                                               float* __restrict__ out) {
    u32 nU = hoff[NBUCKET];
    // Part A: duplicate segments, one wave each (lanes 0..31 carry the 32 float4s)
    int wid = (blockIdx.x * 256 + threadIdx.x) >> 6;
    int nw = (gridDim.x * 256) >> 6;
    int lane = threadIdx.x & 63;
    u32 nd = *dupCount;
    if (nd > DUP_CAP) nd = DUP_CAP;
    for (u32 d = (u32)wid; d < nd; d += (u32)nw) {
        u64 e = dupList[d];
        u32 r = (u32)(e >> 32);
        u32 i0 = (u32)e;
        if (lane < 32) {
            u64 v0 = sorted[i0];
            u32 key = (u32)(v0 >> 32);
            float4 acc = ((const float4*)feats)[(size_t)(u32)v0 * 32 + lane];
            for (u32 j = i0 + 1; j < (u32)N; ++j) {  // ascending original idx == ref order
                u64 vj = sorted[j];
                if ((u32)(vj >> 32) != key) break;
                float4 t = ((const float4*)feats)[(size_t)(u32)vj * 32 + lane];
                acc.x += t.x; acc.y += t.y; acc.z += t.z; acc.w += t.w;
            }
            ((float4*)out)[(size_t)r * 32 + lane] = acc;
        }
    }
    // Part B: zero rows [nU, N)
    u32 tailQuads = ((u32)N - nU) * 32u;
    u32 gt = blockIdx.x * 256 + threadIdx.x;
    u32 tot = gridDim.x * 256;
    for (u32 t = gt; t < tailQuads; t += tot) {
        u32 row = nU + (t >> 5);
        ((float4*)out)[(size_t)row * 32 + (t & 31)] = make_float4(0.f, 0.f, 0.f, 0.f);
    }
}

extern "C" void kernel_launch(void* const* d_in, const int* in_sizes, int n_in,
                              void* d_out, int out_size, void* d_ws, size_t ws_size,
                              hipStream_t stream) {
    const int* coords = (const int*)d_in[0];
    const float* feats = (const float*)d_in[1];
    float* out = (float*)d_out;

    char* w = (char*)d_ws;
    u64* bucketed = (u64*)(w);                              // 2 MiB
    u64* sorted   = (u64*)(w + (size_t)2 * 1024 * 1024);    // 2 MiB
    int* keys     = (int*)(w + (size_t)4 * 1024 * 1024);    // 1 MiB (dead after K3)
    u64* dupList  = (u64*)(w + (size_t)4 * 1024 * 1024);    // reuses keys buffer
    int* inv      = (int*)(w + (size_t)5 * 1024 * 1024);    // 1 MiB
    u32* base     = (u32*)(w + (size_t)6 * 1024 * 1024);
    u32* hist     = base;                 // 16384
    u32* cursor   = base + 16384;         // 16384
    u32* dupCount = base + 32768;         // 1
    u32* bstart   = base + 32832;         // 16385
    u32* hcnt     = bstart + 16385;       // 16384
    u32* hoff     = hcnt + 16384;         // 16385  (hoff[NBUCKET] = nUnique)

    // zero hist + cursor + dupCount (contiguous)
    hipMemsetAsync(hist, 0, (size_t)(32769) * sizeof(u32), stream);

    k_keys_hist<<<N / 256, 256, 0, stream>>>(coords, keys, hist);
    k_scan_buckets<<<1, 1024, 0, stream>>>(hist, bstart);
    k_scatter<<<N / 256, 256, 0, stream>>>(keys, bstart, cursor, bucketed);
    k_sort_buckets<<<1024, 64, 0, stream>>>(bstart, bucketed, sorted, hcnt);
    k_scan_buckets<<<1, 1024, 0, stream>>>(hcnt, hoff);
    k_build_inv<<<1024, 256, 0, stream>>>(bstart, sorted, hoff, inv, dupList, dupCount);
    k_scatter_feats<<<N / ROWS_PER_BLOCK, 256, 0, stream>>>(inv, feats, out);
    k_fixup<<<128, 256, 0, stream>>>(sorted, dupList, dupCount, hoff, feats, out);
}

// Round 6
// 115.295 us; speedup vs baseline: 1.1722x; 1.1722x over previous
//
#include <hip/hip_runtime.h>
#include <hip/hip_bf16.h>
#include <stdint.h>

typedef uint32_t u32;
typedef uint64_t u64;
typedef uint16_t u16;
typedef float f4 __attribute__((ext_vector_type(4)));

// Problem constants (from reference)
constexpr int BATCH = 8;
constexpr int L = 32768;
constexpr int C = 128;            // channels
constexpr int N = BATCH * L;      // 262144 points
constexpr int NBUCKET = 1 << 14;  // buckets on top-14 bits of 30-bit key
constexpr u32 DUP_CAP = 65536;
// key = (batch<<27)|(x<<18)|(y<<9)|z  (30 bits); bucket = key >> 16.
// Buckets partition the key space, so global unique-rank = hoff[bucket] +
// local rank of the distinct key within its bucket. Expected bucket size = 16
// for this input; slow path covers m > 64 (never taken, correctness net).

// ---------------- K1: keys + bucket histogram ----------------
__global__ __launch_bounds__(256) void k_keys_hist(const int* __restrict__ coords,
                                                   u32* __restrict__ keys,
                                                   u32* __restrict__ hist) {
    int i = blockIdx.x * 256 + threadIdx.x;
    int batch = i >> 15;  // i / L
    int x = coords[3 * i + 0];
    int y = coords[3 * i + 1];
    int z = coords[3 * i + 2];
    u32 key = ((u32)batch << 27) | ((u32)x << 18) | ((u32)y << 9) | (u32)z;
    keys[i] = key;
    atomicAdd(&hist[key >> 16], 1u);
}

// ---------------- K2: exclusive scan of 16384 u32 counts (1 block, proven) ----------------
__global__ __launch_bounds__(1024) void k_scan_buckets(const u32* __restrict__ cnt,
                                                       u32* __restrict__ outp) {
    __shared__ u32 s[1024];
    int t = threadIdx.x;
    u32 loc[16];
    u32 sum = 0;
    for (int k = 0; k < 16; ++k) { loc[k] = sum; sum += cnt[t * 16 + k]; }
    s[t] = sum;
    __syncthreads();
    for (int off = 1; off < 1024; off <<= 1) {
        u32 v = (t >= off) ? s[t - off] : 0u;
        __syncthreads();
        s[t] += v;
        __syncthreads();
    }
    u32 base = (t == 0) ? 0u : s[t - 1];
    for (int k = 0; k < 16; ++k) outp[t * 16 + k] = base + loc[k];
    if (t == 1023) outp[NBUCKET] = s[1023];
}

// ---------------- K3: scatter packed (key,idx) into bucket-contiguous order ----------------
__global__ __launch_bounds__(256) void k_scatter(const u32* __restrict__ keys,
                                                 const u32* __restrict__ bstart,
                                                 u32* __restrict__ cursor,
                                                 u64* __restrict__ bucketed) {
    int i = blockIdx.x * 256 + threadIdx.x;
    u32 key = keys[i];
    u32 b = key >> 16;
    u32 pos = bstart[b] + atomicAdd(&cursor[b], 1u);
    bucketed[pos] = ((u64)key << 32) | (u32)i;
}

// ---------------- K4: wave-per-bucket in-register dedup ----------------
// einfo[pos] = localRank(14b) | dup<<14 | first<<15 ; hcnt[b] = #distinct keys.
__global__ __launch_bounds__(256) void k_dedup(const u32* __restrict__ bstart,
                                               const u64* __restrict__ bucketed,
                                               u16* __restrict__ einfo,
                                               u32* __restrict__ hcnt) {
    int wid = (blockIdx.x * 256 + threadIdx.x) >> 6;
    int nw = (gridDim.x * 256) >> 6;
    int lane = threadIdx.x & 63;
    for (int b = wid; b < NBUCKET; b += nw) {
        u32 s0 = bstart[b];
        u32 m = bstart[b + 1] - s0;
        if (m == 0) {
            if (lane == 0) hcnt[b] = 0;
        } else if (m <= 64) {
            // one element per lane, all-pairs via shfl
            u64 v = (lane < (int)m) ? bucketed[s0 + lane] : ~0ull;
            u32 key = (u32)(v >> 32), p = (u32)v;
            bool valid = lane < (int)m;
            bool first = valid;
            bool dup = false;
            for (u32 k = 0; k < m; ++k) {
                u32 kk = (u32)__shfl((int)key, (int)k);
                u32 pk = (u32)__shfl((int)p, (int)k);
                if (valid && (int)k != lane && kk == key) {
                    dup = true;
                    if (pk < p) first = false;  // head = min original idx among equals
                }
            }
            u64 hm = __ballot(valid && first);
            u32 lr = 0;
            for (u32 k = 0; k < m; ++k) {
                u32 kk = (u32)__shfl((int)key, (int)k);
                if (valid && ((hm >> k) & 1ull) && kk < key) lr++;
            }
            if (valid)
                einfo[s0 + lane] =
                    (u16)((lr & 0x3FFF) | (dup ? 0x4000 : 0) | (first ? 0x8000 : 0));
            if (lane == 0) hcnt[b] = (u32)__popcll(hm);
        } else {
            // slow path: per-element O(m^2) (never taken for this input)
            int dc = 0;
            for (u32 j = lane; j < m; j += 64) {
                u64 vj = bucketed[s0 + j];
                u32 kj = (u32)(vj >> 32), pj = (u32)vj;
                bool first = true, dup = false;
                u32 lr = 0;
                for (u32 k = 0; k < m; ++k) {
                    if (k == j) continue;
                    u64 vk = bucketed[s0 + k];
                    u32 kk = (u32)(vk >> 32), pk = (u32)vk;
                    if (kk == kj) {
                        dup = true;
                        if (pk < pj) first = false;
                    } else if (kk < kj) {
                        bool f2 = true;  // count kk once: only at its head element
                        for (u32 k2 = 0; k2 < m; ++k2) {
                            if (k2 == k) continue;
                            u64 v2 = bucketed[s0 + k2];
                            if ((u32)(v2 >> 32) == kk && (u32)v2 < pk) { f2 = false; break; }
                        }
                        if (f2) lr++;
                    }
                }
                einfo[s0 + j] =
                    (u16)((lr & 0x3FFF) | (dup ? 0x4000 : 0) | (first ? 0x8000 : 0));
                dc += first ? 1 : 0;
            }
            for (int off = 32; off > 0; off >>= 1) dc += __shfl_down(dc, off);
            if (lane == 0) hcnt[b] = (u32)dc;
        }
    }
}

// ---------------- K5: elementwise inverse map + duplicate list ----------------
__global__ __launch_bounds__(256) void k_inv(const u64* __restrict__ bucketed,
                                             const u16* __restrict__ einfo,
                                             const u32* __restrict__ hoff,
                                             int* __restrict__ inv,
                                             u64* __restrict__ dupList,
                                             u32* __restrict__ dupCount) {
    int pos = blockIdx.x * 256 + threadIdx.x;
    u64 v = bucketed[pos];
    u32 key = (u32)(v >> 32);
    u32 p = (u32)v;
    u16 e = einfo[pos];
    u32 r = hoff[key >> 16] + (u32)(e & 0x3FFF);
    bool dup = (e & 0x4000) != 0;
    bool first = (e & 0x8000) != 0;
    if (!dup) {
        inv[p] = (int)r;
    } else {
        inv[p] = -1;
        if (first) {
            u32 slot = atomicAdd(dupCount, 1u);
            if (slot < DUP_CAP) dupList[slot] = ((u64)key << 32) | r;
        }
    }
}

// ---------------- K6: streaming scatter + dup fixup + tail zero (disjoint writes) ----------------
constexpr int ROWS_PER_BLOCK = 8;
constexpr int OUT_BLOCKS = N / ROWS_PER_BLOCK;  // 32768

__global__ __launch_bounds__(256) void k_out(const int* __restrict__ inv,
                                             const float* __restrict__ feats,
                                             const u64* __restrict__ bucketed,
                                             const u32* __restrict__ bstart,
                                             const u64* __restrict__ dupList,
                                             const u32* __restrict__ dupCount,
                                             const u32* __restrict__ hoff,
                                             float* __restrict__ out) {
    const f4* F = (const f4*)feats;
    f4* O = (f4*)out;

    // main scatter: one thread = one float4 of one row (proven shape)
    {
        int p = blockIdx.x * ROWS_PER_BLOCK + (threadIdx.x >> 5);
        int q = threadIdx.x & 31;
        int r = inv[p];
        f4 v = F[(size_t)p * 32 + q];
        if (r >= 0) __builtin_nontemporal_store(v, O + (size_t)r * 32 + q);
    }

    // dup-segment fixup: one wave per segment, sum in ascending original index
    {
        int wv = (blockIdx.x * 256 + threadIdx.x) >> 6;
        const int NW = OUT_BLOCKS * 4;
        int lane = threadIdx.x & 63;
        u32 nd = *dupCount;
        if (nd > DUP_CAP) nd = DUP_CAP;
        for (u32 d = (u32)wv; d < nd; d += (u32)NW) {
            u64 e = dupList[d];
            u32 key = (u32)(e >> 32);
            u32 r = (u32)e;
            u32 b = key >> 16;
            u32 s0 = bstart[b];
            u32 m = bstart[b + 1] - s0;
            if (lane < 32) {
                f4 acc = {0.f, 0.f, 0.f, 0.f};
                u32 prevP = 0;
                bool firstIter = true;
                for (;;) {  // next-smallest original index among equal keys
                    u32 best = 0xFFFFFFFFu;
                    for (u32 k = 0; k < m; ++k) {
                        u64 vk = bucketed[s0 + k];
                        if ((u32)(vk >> 32) == key) {
                            u32 pk = (u32)vk;
                            if ((firstIter || pk > prevP) && pk < best) best = pk;
                        }
                    }
                    if (best == 0xFFFFFFFFu) break;
                    acc += F[(size_t)best * 32 + lane];
                    prevP = best;
                    firstIter = false;
                }
                O[(size_t)r * 32 + lane] = acc;
            }
        }
    }

    // tail zero: rows [nUnique, N)
    {
        u32 nU = hoff[NBUCKET];
        u32 tailQuads = ((u32)N - nU) * 32u;
        u32 gt = blockIdx.x * 256 + threadIdx.x;
        const u32 tot = OUT_BLOCKS * 256;
        f4 z = {0.f, 0.f, 0.f, 0.f};
        for (u32 t = gt; t < tailQuads; t += tot) {
            u32 row = nU + (t >> 5);
            O[(size_t)row * 32 + (t & 31)] = z;
        }
    }
}

extern "C" void kernel_launch(void* const* d_in, const int* in_sizes, int n_in,
                              void* d_out, int out_size, void* d_ws, size_t ws_size,
                              hipStream_t stream) {
    const int* coords = (const int*)d_in[0];
    const float* feats = (const float*)d_in[1];
    float* out = (float*)d_out;

    char* w = (char*)d_ws;
    u64* bucketed = (u64*)(w);                                 // 2 MiB
    u32* keys     = (u32*)(w + (size_t)2 * 1024 * 1024);       // 1 MiB
    int* inv      = (int*)(w + (size_t)3 * 1024 * 1024);       // 1 MiB
    u16* einfo    = (u16*)(w + (size_t)4 * 1024 * 1024);       // 512 KiB
    u64* dupList  = (u64*)(w + (size_t)4 * 1024 * 1024 + 512 * 1024);  // 512 KiB
    u32* ctrl     = (u32*)(w + (size_t)5 * 1024 * 1024);       // ~320 KiB
    u32* hist     = ctrl;                  // 16384
    u32* cursor   = ctrl + 16384;          // 16384
    u32* dupCount = ctrl + 32768;          // 1
    u32* bstart   = ctrl + 32769;          // 16385
    u32* hcnt     = ctrl + 49154;          // 16384
    u32* hoff     = ctrl + 65538;          // 16385 (hoff[NBUCKET] = nUnique)

    // zero hist + cursor + dupCount (contiguous 32769 words)
    hipMemsetAsync(hist, 0, (size_t)32769 * sizeof(u32), stream);

    k_keys_hist<<<N / 256, 256, 0, stream>>>(coords, keys, hist);
    k_scan_buckets<<<1, 1024, 0, stream>>>(hist, bstart);
    k_scatter<<<N / 256, 256, 0, stream>>>(keys, bstart, cursor, bucketed);
    k_dedup<<<4096, 256, 0, stream>>>(bstart, bucketed, einfo, hcnt);
    k_scan_buckets<<<1, 1024, 0, stream>>>(hcnt, hoff);
    k_inv<<<N / 256, 256, 0, stream>>>(bucketed, einfo, hoff, inv, dupList, dupCount);
    k_out<<<OUT_BLOCKS, 256, 0, stream>>>(inv, feats, bucketed, bstart, dupList,
                                          dupCount, hoff, out);
}